// Round 4
// baseline (78525.104 us; speedup 1.0000x reference)
//
#include <hip/hip_runtime.h>
#include <hip/hip_bf16.h>

typedef unsigned int u32;

#define NBLK 512
#define NTHR 256

#define BATCH 32
#define TENC  200
#define MEMD  512
#define NMELS 80
#define TMELS 800
#define NSTEP 400

// ws float offsets (after 256B reserved region)
#define OFF_AH    0          // 2 * 32*1024 (double buffered)
#define OFF_ACS   65536
#define OFF_DH    98304
#define OFF_DCS   131072
#define OFF_CTX   163840     // 32*512
#define OFF_AW    180224     // 32*200
#define OFF_FBUF  186624     // 32*200*8
#define OFF_PBUF  237824     // 32*200
#define OFF_GPART 244224     // 32*4096 ([row*32+b])
#define OFF_X     375296     // 400*32*256
#define ZERO_CNT  180224     // zero [0, OFF_AW)

struct KArgs {
  const float *mels, *memory, *pW1, *pb1, *pW2, *pb2;
  const float *aWih, *aWhh, *abih, *abhh;
  const float *Wq, *bq, *V, *F, *U, *T, *Tb, *vv, *prior;
  const float *dWih, *dWhh, *dbih, *dbhh, *acW, *acb;
  float *out;
  float *ws;
};

__device__ __forceinline__ float sigf(float x) {
  x = fminf(fmaxf(x, -30.f), 30.f);
  return 1.0f / (1.0f + __expf(-x));
}
__device__ __forceinline__ float ftanh(float x) {
  x = fminf(fmaxf(x, -15.f), 15.f);
  float e = __expf(2.f * x);
  return (e - 1.f) / (e + 1.f);
}

// stage chunk: sm[i*257 + t] = src[i*stride + off + t], i in [0,32)
__device__ __forceinline__ void stage32(float* sm, const float* src, int stride, int off) {
  const int t = threadIdx.x;
  #pragma unroll 8
  for (int i = 0; i < 32; ++i) sm[i*257 + t] = src[i*stride + off + t];
}

__device__ __forceinline__ void loadxin(const float* sm, float* xin) {
  const int b = threadIdx.x & 31, seg = threadIdx.x >> 5;
  const float* xb = sm + b*257 + seg*32;
  #pragma unroll
  for (int k = 0; k < 32; ++k) xin[k] = xb[k];
}

__device__ __forceinline__ float dot32(const float* xin, const float* w) {
  const float4* wp = (const float4*)w;
  float acc = 0.f;
  #pragma unroll
  for (int q = 0; q < 8; ++q) {
    float4 wv = wp[q];
    acc += wv.x*xin[q*4+0] + wv.y*xin[q*4+1] + wv.z*xin[q*4+2] + wv.w*xin[q*4+3];
  }
  return acc;
}

// after per-(b,seg) acc[8], return per-(r=t>>5, b=t&31) total
__device__ __forceinline__ float reduce8(float* smred, const float* acc) {
  const int t = threadIdx.x;
  const int b = t & 31, seg = t >> 5;
  __syncthreads();
  #pragma unroll
  for (int r = 0; r < 8; ++r) smred[(seg*8 + r)*32 + b] = acc[r];
  __syncthreads();
  const int r2 = t >> 5, b2 = t & 31;
  float tot = 0.f;
  #pragma unroll
  for (int sgi = 0; sgi < 8; ++sgi) tot += smred[(sgi*8 + r2)*32 + b2];
  return tot;
}

__device__ __forceinline__ void j3_outproj(const KArgs& a, float* sm, float* smred,
                                           const float* dh, const float* ctx,
                                           int bid, int sprev) {
  const int tid = threadIdx.x;
  float acc[8];
  #pragma unroll
  for (int r = 0; r < 8; ++r) acc[r] = 0.f;
  for (int kc = 0; kc < 6; ++kc) {
    __syncthreads();
    if (kc < 4) stage32(sm, dh, 1024, kc*256);
    else        stage32(sm, ctx, 512, (kc-4)*256);
    __syncthreads();
    float xin[32];
    loadxin(sm, xin);
    const int seg = tid >> 5;
    #pragma unroll
    for (int r = 0; r < 8; ++r) {
      int rr = bid*8 + r;
      acc[r] += dot32(xin, a.acW + rr*1536 + kc*256 + seg*32);
    }
  }
  float tot = reduce8(smred, acc);
  const int r2 = tid >> 5, b2 = tid & 31;
  const int rr = bid*8 + r2;
  tot += a.acb[rr];
  const int c = rr >> 1, r_ = rr & 1;
  a.out[(b2*NMELS + c)*TMELS + sprev*2 + r_] = tot;
}

__device__ __forceinline__ void dca_step(const KArgs& a, float* sm, int b, int s,
                                         const float* ah_new, float* aw,
                                         const float* fbuf, const float* pbuf, float* ctx) {
  const int tid = threadIdx.x;
  float* s_ah  = sm;            // 1024
  float* s_awp = sm + 1024;     // 220 (padded aw_prev)
  float* s_q   = sm + 1248;     // 128
  float* s_G   = sm + 1376;     // 176
  float* s_e   = sm + 1552;     // 208
  float* s_gg  = sm + 1760;     // 1600 [pos*8+d]
  float* s_ff  = sm + 3360;     // 1600 [pos*8+j]
  float* s_red = sm + 4960;     // 256
  float* s_awn = sm + 5216;     // 200
  __syncthreads();
  for (int i = tid; i < 1024; i += NTHR) s_ah[i] = ah_new[b*1024 + i];
  if (tid < 220) s_awp[tid] = (tid >= 10 && tid < 210) ? aw[b*TENC + tid - 10] : 0.f;
  for (int i = tid; i < 1600; i += NTHR) s_ff[i] = fbuf[b*1600 + i];
  __syncthreads();
  // q = tanh(Wq @ ah + bq), split K across 2 halves
  {
    const int o = tid & 127, half = tid >> 7;
    const float4* wq = (const float4*)(a.Wq + o*1024 + half*512);
    const float* xa = s_ah + half*512;
    float p = 0.f;
    #pragma unroll 8
    for (int q4 = 0; q4 < 128; ++q4) {
      float4 w = wq[q4];
      p += w.x*xa[q4*4+0] + w.y*xa[q4*4+1] + w.z*xa[q4*4+2] + w.w*xa[q4*4+3];
    }
    s_red[tid] = p;
  }
  __syncthreads();
  if (tid < 128) s_q[tid] = ftanh(s_red[tid] + s_red[128 + tid] + a.bq[tid]);
  __syncthreads();
  // G = q @ V^T  (168 outputs)
  if (tid < 168) {
    const float4* vp = (const float4*)(a.V + tid*128);
    float p = 0.f;
    #pragma unroll
    for (int q4 = 0; q4 < 32; ++q4) {
      float4 w = vp[q4];
      const float* xq = s_q + q4*4;
      p += w.x*xq[0] + w.y*xq[1] + w.z*xq[2] + w.w*xq[3];
    }
    s_G[tid] = p;
  }
  __syncthreads();
  // dynamic conv: g[pos][d]
  for (int idx = tid; idx < 1600; idx += NTHR) {
    const int pos = idx >> 3, d = idx & 7;
    float p = 0.f;
    #pragma unroll
    for (int tau = 0; tau < 21; ++tau) p += s_awp[pos + tau] * s_G[d*21 + tau];
    s_gg[idx] = p;
  }
  __syncthreads();
  // energies: e[pos] = v . tanh(U f + T g + Tb) + p[pos]
  #pragma unroll 1
  for (int ro = 0; ro < 4; ++ro) {
    const int pos = ro*64 + (tid >> 2), sub = tid & 3;
    float av = 0.f;
    if (pos < 200) {
      const float* fpos = s_ff + pos*8;
      const float* gpos = s_gg + pos*8;
      #pragma unroll 4
      for (int fi = 0; fi < 32; ++fi) {
        const int ff = sub*32 + fi;
        const float4* Up = (const float4*)(a.U + ff*8);
        const float4* Tp = (const float4*)(a.T + ff*8);
        float4 u0 = Up[0], u1 = Up[1], t0 = Tp[0], t1 = Tp[1];
        float h = a.Tb[ff];
        h += u0.x*fpos[0] + u0.y*fpos[1] + u0.z*fpos[2] + u0.w*fpos[3]
           + u1.x*fpos[4] + u1.y*fpos[5] + u1.z*fpos[6] + u1.w*fpos[7];
        h += t0.x*gpos[0] + t0.y*gpos[1] + t0.z*gpos[2] + t0.w*gpos[3]
           + t1.x*gpos[4] + t1.y*gpos[5] + t1.z*gpos[6] + t1.w*gpos[7];
        av += a.vv[ff] * ftanh(h);
      }
    }
    av += __shfl_xor(av, 1);
    av += __shfl_xor(av, 2);
    if (sub == 0 && pos < 200) s_e[pos] = av + pbuf[b*TENC + pos];
  }
  __syncthreads();
  // softmax over 200
  float mval = (tid < 200) ? s_e[tid] : -1e30f;
  #pragma unroll
  for (int off = 32; off > 0; off >>= 1) mval = fmaxf(mval, __shfl_xor(mval, off));
  if ((tid & 63) == 0) s_red[tid >> 6] = mval;
  __syncthreads();
  const float m = fmaxf(fmaxf(s_red[0], s_red[1]), fmaxf(s_red[2], s_red[3]));
  const float ex = (tid < 200) ? __expf(s_e[tid] - m) : 0.f;
  float sv = ex;
  #pragma unroll
  for (int off = 32; off > 0; off >>= 1) sv += __shfl_xor(sv, off);
  if ((tid & 63) == 0) s_red[4 + (tid >> 6)] = sv;
  __syncthreads();
  const float inv = 1.f / (s_red[4] + s_red[5] + s_red[6] + s_red[7]);
  if (tid < 200) {
    const float awv = ex * inv;
    aw[b*TENC + tid] = awv;
    s_awn[tid] = awv;
    a.out[2048000 + b*80000 + tid*400 + s] = awv;
  }
  __syncthreads();
  // ctx = aw_new @ memory[b]
  #pragma unroll 1
  for (int d = tid; d < 512; d += NTHR) {
    const float* mb = a.memory + b*102400 + d;
    float p = 0.f;
    #pragma unroll 4
    for (int t2 = 0; t2 < 200; ++t2) p += s_awn[t2] * mb[t2*512];
    ctx[b*512 + d] = p;
  }
}

// ======== kernel 0: zero state + one-hot aw ========
__global__ __launch_bounds__(NTHR) void init_kernel(KArgs a) {
  const int gtid = blockIdx.x*NTHR + threadIdx.x;
  float* ws = a.ws;
  for (int i = gtid; i < ZERO_CNT; i += NBLK*NTHR) ws[i] = 0.f;
  float* aw = ws + OFF_AW;
  for (int i = gtid; i < BATCH*TENC; i += NBLK*NTHR) aw[i] = ((i % TENC) == 0) ? 1.f : 0.f;
}

// ======== kernel 1: prenet for all (s,b) pairs; grid 12800 ========
__global__ __launch_bounds__(NTHR) void prenet_kernel(KArgs a) {
  __shared__ float sm[384];
  const int tid = threadIdx.x;
  const int pair = blockIdx.x;           // s*32 + b
  const int s = pair >> 5, b = pair & 31;
  float* X = a.ws + OFF_X;
  if (tid < 80) {
    float v = 0.f;
    if (s > 0) v = a.mels[(b*NMELS + tid)*TMELS + 2*s - 1];
    sm[tid] = v;
  }
  __syncthreads();
  float a1 = a.pb1[tid];
  #pragma unroll 4
  for (int k = 0; k < 80; ++k) a1 += a.pW1[tid*80 + k] * sm[k];
  a1 = fmaxf(a1, 0.f);
  __syncthreads();
  sm[128 + tid] = a1;
  __syncthreads();
  float a2 = a.pb2[tid];
  #pragma unroll 4
  for (int k = 0; k < 256; ++k) a2 += a.pW2[tid*256 + k] * sm[128 + k];
  a2 = fmaxf(a2, 0.f);
  X[(s*BATCH + b)*256 + tid] = a2;
}

// ======== phase 1 kernel ========
__global__ __launch_bounds__(NTHR) void p1_kernel(KArgs a, int s) {
  __shared__ float sm[10528];
  float* smred = sm + 8224;
  float* smg   = sm + 10272;
  const int tid = threadIdx.x;
  const int bid = blockIdx.x;
  float* ws = a.ws;
  float* ah_prev = ws + OFF_AH + ((s & 1) ? 32768 : 0);
  float* ah_new  = ws + OFF_AH + ((s & 1) ? 0 : 32768);
  float* acs = ws + OFF_ACS;
  float* dh  = ws + OFF_DH;
  float* ctx = ws + OFF_CTX;
  float* aw  = ws + OFF_AW;
  float* fbuf  = ws + OFF_FBUF;
  float* pbuf  = ws + OFF_PBUF;
  float* gpart = ws + OFF_GPART;
  float* X     = ws + OFF_X;

  // J1: attn LSTM (units u0,u0+1; rows rr = g*1024 + j)
  {
    const int u0 = bid*2;
    float acc[8];
    #pragma unroll
    for (int r = 0; r < 8; ++r) acc[r] = 0.f;
    const float* Xs = X + s*BATCH*256;
    for (int kc = 0; kc < 7; ++kc) {
      __syncthreads();
      if (kc < 2)        stage32(sm, ctx, 512, kc*256);
      else if (kc == 2)  stage32(sm, Xs, 256, 0);
      else               stage32(sm, ah_prev, 1024, (kc-3)*256);
      __syncthreads();
      float xin[32];
      loadxin(sm, xin);
      const int seg = tid >> 5;
      #pragma unroll
      for (int r = 0; r < 8; ++r) {
        const int rr = (r>>1)*1024 + u0 + (r&1);
        const float* wr = (kc < 3) ? (a.aWih + rr*768 + kc*256 + seg*32)
                                   : (a.aWhh + rr*1024 + (kc-3)*256 + seg*32);
        acc[r] += dot32(xin, wr);
      }
    }
    float tot = reduce8(smred, acc);
    {
      const int r2 = tid >> 5, b2 = tid & 31;
      const int rr = (r2>>1)*1024 + u0 + (r2&1);
      tot += a.abih[rr] + a.abhh[rr];
      smg[r2*32 + b2] = tot;
    }
    __syncthreads();
    if (tid < 64) {
      const int u = tid >> 5, b2 = tid & 31;
      const int j = u0 + u;
      const float gi = smg[(0+u)*32+b2], gf = smg[(2+u)*32+b2];
      const float gg = smg[(4+u)*32+b2], go = smg[(6+u)*32+b2];
      const float c = sigf(gf)*acs[b2*1024+j] + sigf(gi)*ftanh(gg);
      acs[b2*1024+j] = c;
      ah_new[b2*1024+j] = sigf(go)*ftanh(c);
    }
  }
  // J2: gpart = dh @ dWhh^T + bih + bhh
  {
    float acc[8];
    #pragma unroll
    for (int r = 0; r < 8; ++r) acc[r] = 0.f;
    for (int kc = 0; kc < 4; ++kc) {
      __syncthreads();
      stage32(sm, dh, 1024, kc*256);
      __syncthreads();
      float xin[32];
      loadxin(sm, xin);
      const int seg = tid >> 5;
      #pragma unroll
      for (int r = 0; r < 8; ++r) {
        const int rr = bid*8 + r;
        acc[r] += dot32(xin, a.dWhh + rr*1024 + kc*256 + seg*32);
      }
    }
    float tot = reduce8(smred, acc);
    const int r2 = tid >> 5, b2 = tid & 31;
    const int rr = bid*8 + r2;
    tot += a.dbih[rr] + a.dbhh[rr];
    gpart[rr*32 + b2] = tot;
  }
  // J3: previous step's output projection (blocks 0..19)
  if (bid < 20 && s > 0) j3_outproj(a, sm, smred, dh, ctx, bid, s - 1);
  // J4: static conv + log-prior (blocks 480..511, one batch each)
  if (bid >= 480) {
    const int b4 = bid - 480;
    __syncthreads();
    if (tid < 220) sm[tid] = (tid >= 10 && tid < 210) ? aw[b4*TENC + tid - 10] : 0.f;
    __syncthreads();
    if (tid < 200) {
      #pragma unroll
      for (int j = 0; j < 8; ++j) {
        float p = 0.f;
        #pragma unroll
        for (int tau = 0; tau < 21; ++tau) p += sm[tid + tau] * a.F[j*21 + tau];
        fbuf[(b4*TENC + tid)*8 + j] = p;
      }
      float pp = 0.f;
      #pragma unroll
      for (int tau = 0; tau < 11; ++tau) pp += sm[tid + tau] * a.prior[tau];
      pbuf[b4*TENC + tid] = __logf(fmaxf(pp, 1e-6f));
    }
  }
}

// ======== phase 2 kernel ========
__global__ __launch_bounds__(NTHR) void p2_kernel(KArgs a, int s) {
  __shared__ float sm[10528];
  float* smred = sm + 8224;
  const int tid = threadIdx.x;
  const int bid = blockIdx.x;
  float* ws = a.ws;
  float* ah_new = ws + OFF_AH + ((s & 1) ? 0 : 32768);
  float* ctx = ws + OFF_CTX;
  float* aw  = ws + OFF_AW;
  float* fbuf  = ws + OFF_FBUF;
  float* pbuf  = ws + OFF_PBUF;
  float* gpart = ws + OFF_GPART;

  if (bid < 32) {
    dca_step(a, sm, bid, s, ah_new, aw, fbuf, pbuf, ctx);
  } else {
    const int cjob = bid - 32;
    #pragma unroll 1
    for (int pass = 0; pass < 2; ++pass) {
      if (pass == 1 && cjob >= 32) break;
      const int c = (pass == 0) ? cjob : (480 + cjob);
      float acc[8];
      #pragma unroll
      for (int r = 0; r < 8; ++r) acc[r] = 0.f;
      for (int kc = 0; kc < 4; ++kc) {
        __syncthreads();
        stage32(sm, ah_new, 1024, kc*256);
        __syncthreads();
        float xin[32];
        loadxin(sm, xin);
        const int seg = tid >> 5;
        #pragma unroll
        for (int r = 0; r < 8; ++r) {
          const int rr = c*8 + r;
          acc[r] += dot32(xin, a.dWih + rr*1536 + kc*256 + seg*32);
        }
      }
      float tot = reduce8(smred, acc);
      const int r2 = tid >> 5, b2 = tid & 31;
      const int rr = c*8 + r2;
      gpart[rr*32 + b2] += tot;
    }
  }
}

// ======== phase 3 kernel: finish dec LSTM ========
__global__ __launch_bounds__(NTHR) void p3_kernel(KArgs a, int s) {
  __shared__ float sm[10528];
  float* smred = sm + 8224;
  float* smg   = sm + 10272;
  const int tid = threadIdx.x;
  const int bid = blockIdx.x;
  float* ws = a.ws;
  float* dh  = ws + OFF_DH;
  float* dcs = ws + OFF_DCS;
  float* ctx = ws + OFF_CTX;
  float* gpart = ws + OFF_GPART;

  const int u0 = bid*2;
  float acc[8];
  #pragma unroll
  for (int r = 0; r < 8; ++r) acc[r] = 0.f;
  for (int kc = 0; kc < 2; ++kc) {
    __syncthreads();
    stage32(sm, ctx, 512, kc*256);
    __syncthreads();
    float xin[32];
    loadxin(sm, xin);
    const int seg = tid >> 5;
    #pragma unroll
    for (int r = 0; r < 8; ++r) {
      const int rr = (r>>1)*1024 + u0 + (r&1);
      acc[r] += dot32(xin, a.dWih + rr*1536 + 1024 + kc*256 + seg*32);
    }
  }
  float tot = reduce8(smred, acc);
  {
    const int r2 = tid >> 5, b2 = tid & 31;
    const int rr = (r2>>1)*1024 + u0 + (r2&1);
    tot += gpart[rr*32 + b2];
    smg[r2*32 + b2] = tot;
  }
  __syncthreads();
  if (tid < 64) {
    const int u = tid >> 5, b2 = tid & 31;
    const int j = u0 + u;
    const float gi = smg[(0+u)*32+b2], gf = smg[(2+u)*32+b2];
    const float gg = smg[(4+u)*32+b2], go = smg[(6+u)*32+b2];
    const float c = sigf(gf)*dcs[b2*1024+j] + sigf(gi)*ftanh(gg);
    dcs[b2*1024+j] = c;
    dh[b2*1024+j] = sigf(go)*ftanh(c);
  }
}

// ======== epilogue: final step's output projection (grid 20) ========
__global__ __launch_bounds__(NTHR) void ep_kernel(KArgs a) {
  __shared__ float sm[10528];
  float* smred = sm + 8224;
  float* ws = a.ws;
  j3_outproj(a, sm, smred, ws + OFF_DH, ws + OFF_CTX, blockIdx.x, NSTEP - 1);
}

extern "C" void kernel_launch(void* const* d_in, const int* in_sizes, int n_in,
                              void* d_out, int out_size, void* d_ws, size_t ws_size,
                              hipStream_t stream) {
  (void)in_sizes; (void)n_in; (void)out_size; (void)ws_size;
  KArgs a;
  a.mels   = (const float*)d_in[0];
  a.memory = (const float*)d_in[1];
  a.pW1 = (const float*)d_in[2];  a.pb1 = (const float*)d_in[3];
  a.pW2 = (const float*)d_in[4];  a.pb2 = (const float*)d_in[5];
  a.aWih = (const float*)d_in[6]; a.aWhh = (const float*)d_in[7];
  a.abih = (const float*)d_in[8]; a.abhh = (const float*)d_in[9];
  a.Wq = (const float*)d_in[10];  a.bq = (const float*)d_in[11];
  a.V  = (const float*)d_in[12];  a.F  = (const float*)d_in[13];
  a.U  = (const float*)d_in[14];  a.T  = (const float*)d_in[15];
  a.Tb = (const float*)d_in[16];  a.vv = (const float*)d_in[17];
  a.prior = (const float*)d_in[18];
  a.dWih = (const float*)d_in[19]; a.dWhh = (const float*)d_in[20];
  a.dbih = (const float*)d_in[21]; a.dbhh = (const float*)d_in[22];
  a.acW  = (const float*)d_in[23]; a.acb  = (const float*)d_in[24];
  a.out = (float*)d_out;
  a.ws  = (float*)((char*)d_ws + 256);

  hipLaunchKernelGGL(init_kernel, dim3(NBLK), dim3(NTHR), 0, stream, a);
  hipLaunchKernelGGL(prenet_kernel, dim3(NSTEP*BATCH), dim3(NTHR), 0, stream, a);
  for (int s = 0; s < NSTEP; ++s) {
    hipLaunchKernelGGL(p1_kernel, dim3(NBLK), dim3(NTHR), 0, stream, a, s);
    hipLaunchKernelGGL(p2_kernel, dim3(NBLK), dim3(NTHR), 0, stream, a, s);
    hipLaunchKernelGGL(p3_kernel, dim3(NBLK), dim3(NTHR), 0, stream, a, s);
  }
  hipLaunchKernelGGL(ep_kernel, dim3(20), dim3(NTHR), 0, stream, a);
}

// Round 5
// 61561.975 us; speedup vs baseline: 1.2755x; 1.2755x over previous
//
#include <hip/hip_runtime.h>
#include <hip/hip_bf16.h>

typedef unsigned short u16;
typedef unsigned int   u32;

#define NTHR 256

#define BATCH 32
#define TENC  200
#define NMELS 80
#define TMELS 800
#define NSTEP 400

// ---- ws float offsets (after 256B reserved region) ----
#define OFF_AH    0          // 2 * 32*1024 (double buffered)
#define OFF_ACS   65536
#define OFF_DH    98304
#define OFF_DCS   131072
#define OFF_CTX   163840     // 32*512
#define OFF_AW    180224     // 32*200
#define OFF_FBUF  186624     // 32*200*8
#define OFF_PBUF  237824     // 32*200
#define OFF_GPART 244224     // 32*4096 ([row*32+b])
#define OFF_X     375296     // 400*32*256
#define FLOAT_END 3652096    // OFF_X + 3276800
#define ZERO_CNT  180224     // zero [0, OFF_AW)

// ---- bf16 region offsets (u16 indices, base = ws + FLOAT_END) ----
#define B_AWIH 0            // 4096*768
#define B_AWHH 3145728      // 4096*1024
#define B_DWIH 7340032      // 4096*1536
#define B_DWHH 13631488     // 4096*1024
#define B_ACW  17825792     // 160*1536
#define B_WQ   18071552     // 128*1024
#define B_MEMT 18202624     // 32*512*200  [b][d][t]
// end: 21479424 u16 (~43 MB); total ws use ~57.6 MB

struct KArgs {
  const float *mels, *memory, *pW1, *pb1, *pW2, *pb2;
  const float *aWih, *aWhh, *abih, *abhh;
  const float *Wq, *bq, *V, *F, *U, *T, *Tb, *vv, *prior;
  const float *dWih, *dWhh, *dbih, *dbhh, *acW, *acb;
  float *out;
  float *ws;
  u16   *wb;
};

__device__ __forceinline__ float sigf(float x) {
  x = fminf(fmaxf(x, -30.f), 30.f);
  return 1.0f / (1.0f + __expf(-x));
}
__device__ __forceinline__ float ftanh(float x) {
  x = fminf(fmaxf(x, -15.f), 15.f);
  float e = __expf(2.f * x);
  return (e - 1.f) / (e + 1.f);
}
__device__ __forceinline__ float blo(u32 u) {
  union { u32 i; float f; } v; v.i = u << 16; return v.f;
}
__device__ __forceinline__ float bhi(u32 u) {
  union { u32 i; float f; } v; v.i = u & 0xffff0000u; return v.f;
}
__device__ __forceinline__ u16 f2b(float x) {
  __hip_bfloat16 h = __float2bfloat16(x);
  return *reinterpret_cast<u16*>(&h);
}

// direct activation load: 32 consecutive floats (16B-aligned)
__device__ __forceinline__ void loadx(const float* src, float* xin) {
  const float4* p = (const float4*)src;
  #pragma unroll
  for (int q = 0; q < 8; ++q) {
    float4 v = p[q];
    xin[q*4+0] = v.x; xin[q*4+1] = v.y; xin[q*4+2] = v.z; xin[q*4+3] = v.w;
  }
}

// 32-K dot with bf16 weight row-chunk (4 uint4 = 32 bf16)
__device__ __forceinline__ float dot32b(const float* xin, const u16* w) {
  const uint4* wp = (const uint4*)w;
  float acc = 0.f;
  #pragma unroll
  for (int q = 0; q < 4; ++q) {
    uint4 wv = wp[q];
    acc += blo(wv.x)*xin[q*8+0] + bhi(wv.x)*xin[q*8+1]
         + blo(wv.y)*xin[q*8+2] + bhi(wv.y)*xin[q*8+3]
         + blo(wv.z)*xin[q*8+4] + bhi(wv.z)*xin[q*8+5]
         + blo(wv.w)*xin[q*8+6] + bhi(wv.w)*xin[q*8+7];
  }
  return acc;
}

// per-(b,seg) acc[8] -> per-(r=t>>5, b=t&31) total; smred: 2048 floats
__device__ __forceinline__ float reduce8(float* smred, const float* acc) {
  const int t = threadIdx.x;
  const int b = t & 31, seg = t >> 5;
  __syncthreads();
  #pragma unroll
  for (int r = 0; r < 8; ++r) smred[(seg*8 + r)*32 + b] = acc[r];
  __syncthreads();
  const int r2 = t >> 5, b2 = t & 31;
  float tot = 0.f;
  #pragma unroll
  for (int sgi = 0; sgi < 8; ++sgi) tot += smred[(sgi*8 + r2)*32 + b2];
  return tot;
}

// output projection for step sprev (8 rows per block), bf16 acW
__device__ __forceinline__ void outproj(const KArgs& a, float* smred,
                                        const float* dh, const float* ctx,
                                        int pb, int sprev) {
  const int tid = threadIdx.x;
  const int b = tid & 31, seg = tid >> 5;
  const u16* wb = a.wb;
  float acc[8];
  #pragma unroll
  for (int r = 0; r < 8; ++r) acc[r] = 0.f;
  #pragma unroll 2
  for (int kc = 0; kc < 6; ++kc) {
    const float* src = (kc < 4) ? (dh + b*1024 + kc*256) : (ctx + b*512 + (kc-4)*256);
    float xin[32];
    loadx(src + seg*32, xin);
    #pragma unroll
    for (int r = 0; r < 8; ++r) {
      const int rr = pb*8 + r;
      acc[r] += dot32b(xin, wb + B_ACW + rr*1536 + kc*256 + seg*32);
    }
  }
  float tot = reduce8(smred, acc);
  const int r2 = tid >> 5, b2 = tid & 31;
  const int rr = pb*8 + r2;
  tot += a.acb[rr];
  a.out[(b2*NMELS + (rr >> 1))*TMELS + sprev*2 + (rr & 1)] = tot;
}

// ======== init: zero state + one-hot aw ========
__global__ __launch_bounds__(NTHR) void init_kernel(KArgs a) {
  const int gtid = blockIdx.x*NTHR + threadIdx.x;
  const int str = gridDim.x*NTHR;
  float* ws = a.ws;
  for (int i = gtid; i < ZERO_CNT; i += str) ws[i] = 0.f;
  float* aw = ws + OFF_AW;
  for (int i = gtid; i < BATCH*TENC; i += str) aw[i] = ((i % TENC) == 0) ? 1.f : 0.f;
}

// ======== convert weights to bf16 (+ memory transpose) ========
__global__ __launch_bounds__(NTHR) void conv_kernel(KArgs a) {
  const int gtid = blockIdx.x*NTHR + threadIdx.x;
  const int str = gridDim.x*NTHR;
  u16* wb = a.wb;
  for (int i = gtid; i < 3145728; i += str) wb[B_AWIH + i] = f2b(a.aWih[i]);
  for (int i = gtid; i < 4194304; i += str) wb[B_AWHH + i] = f2b(a.aWhh[i]);
  for (int i = gtid; i < 6291456; i += str) wb[B_DWIH + i] = f2b(a.dWih[i]);
  for (int i = gtid; i < 4194304; i += str) wb[B_DWHH + i] = f2b(a.dWhh[i]);
  for (int i = gtid; i < 245760;  i += str) wb[B_ACW  + i] = f2b(a.acW[i]);
  for (int i = gtid; i < 131072;  i += str) wb[B_WQ   + i] = f2b(a.Wq[i]);
  for (int i = gtid; i < 3276800; i += str) {
    const int b = i / 102400, rem = i - b*102400;
    const int d = rem / 200, t = rem - d*200;
    wb[B_MEMT + i] = f2b(a.memory[b*102400 + t*512 + d]);
  }
}

// ======== prenet for all (s,b) pairs; grid 12800 ========
__global__ __launch_bounds__(NTHR) void prenet_kernel(KArgs a) {
  __shared__ float sm[384];
  const int tid = threadIdx.x;
  const int pair = blockIdx.x;           // s*32 + b
  const int s = pair >> 5, b = pair & 31;
  float* X = a.ws + OFF_X;
  if (tid < 80) {
    float v = 0.f;
    if (s > 0) v = a.mels[(b*NMELS + tid)*TMELS + 2*s - 1];
    sm[tid] = v;
  }
  __syncthreads();
  float a1 = a.pb1[tid];
  #pragma unroll 4
  for (int k = 0; k < 80; ++k) a1 += a.pW1[tid*80 + k] * sm[k];
  a1 = fmaxf(a1, 0.f);
  __syncthreads();
  sm[128 + tid] = a1;
  __syncthreads();
  float a2 = a.pb2[tid];
  #pragma unroll 4
  for (int k = 0; k < 256; ++k) a2 += a.pW2[tid*256 + k] * sm[128 + k];
  a2 = fmaxf(a2, 0.f);
  X[(s*BATCH + b)*256 + tid] = a2;
}

// ======== DCA (one block per batch) ========
__device__ __forceinline__ void dca_step(const KArgs& a, float* sm, int b, int s,
                                         const float* ah_new, float* aw,
                                         const float* fbuf, const float* pbuf, float* ctx) {
  const int tid = threadIdx.x;
  const u16* wb = a.wb;
  float* s_ah  = sm;            // 1024
  float* s_awp = sm + 1024;     // 224 (padded aw_prev)
  float* s_q   = sm + 1248;     // 128
  float* s_G   = sm + 1376;     // 176
  float* s_e   = sm + 1552;     // 208
  float* s_gg  = sm + 1760;     // 1600 [pos*8+d]
  float* s_ff  = sm + 3360;     // 1600 [pos*8+j]
  float* s_red = sm + 4960;     // 256
  float* s_awn = sm + 5216;     // 200
  for (int i = tid; i < 1024; i += NTHR) s_ah[i] = ah_new[b*1024 + i];
  if (tid < 220) s_awp[tid] = (tid >= 10 && tid < 210) ? aw[b*TENC + tid - 10] : 0.f;
  for (int i = tid; i < 1600; i += NTHR) s_ff[i] = fbuf[b*1600 + i];
  __syncthreads();
  // q = tanh(Wq @ ah + bq), bf16 Wq, split K across 2 halves
  {
    const int o = tid & 127, half = tid >> 7;
    const uint4* wq = (const uint4*)(wb + B_WQ + o*1024 + half*512);
    const float* xa = s_ah + half*512;
    float p = 0.f;
    #pragma unroll 8
    for (int q8 = 0; q8 < 64; ++q8) {
      uint4 w = wq[q8];
      const float* xq = xa + q8*8;
      p += blo(w.x)*xq[0] + bhi(w.x)*xq[1] + blo(w.y)*xq[2] + bhi(w.y)*xq[3]
         + blo(w.z)*xq[4] + bhi(w.z)*xq[5] + blo(w.w)*xq[6] + bhi(w.w)*xq[7];
    }
    s_red[tid] = p;
  }
  __syncthreads();
  if (tid < 128) s_q[tid] = ftanh(s_red[tid] + s_red[128 + tid] + a.bq[tid]);
  __syncthreads();
  // G = q @ V^T  (168 outputs, fp32 V)
  if (tid < 168) {
    const float4* vp = (const float4*)(a.V + tid*128);
    float p = 0.f;
    #pragma unroll
    for (int q4 = 0; q4 < 32; ++q4) {
      float4 w = vp[q4];
      const float* xq = s_q + q4*4;
      p += w.x*xq[0] + w.y*xq[1] + w.z*xq[2] + w.w*xq[3];
    }
    s_G[tid] = p;
  }
  __syncthreads();
  // dynamic conv: g[pos][d]
  for (int idx = tid; idx < 1600; idx += NTHR) {
    const int pos = idx >> 3, d = idx & 7;
    float p = 0.f;
    #pragma unroll
    for (int tau = 0; tau < 21; ++tau) p += s_awp[pos + tau] * s_G[d*21 + tau];
    s_gg[idx] = p;
  }
  __syncthreads();
  // energies: e[pos] = v . tanh(U f + T g + Tb) + p[pos]
  #pragma unroll 1
  for (int ro = 0; ro < 4; ++ro) {
    const int pos = ro*64 + (tid >> 2), sub = tid & 3;
    float av = 0.f;
    if (pos < 200) {
      const float* fpos = s_ff + pos*8;
      const float* gpos = s_gg + pos*8;
      #pragma unroll 4
      for (int fi = 0; fi < 32; ++fi) {
        const int ff = sub*32 + fi;
        const float4* Up = (const float4*)(a.U + ff*8);
        const float4* Tp = (const float4*)(a.T + ff*8);
        float4 u0 = Up[0], u1 = Up[1], t0 = Tp[0], t1 = Tp[1];
        float h = a.Tb[ff];
        h += u0.x*fpos[0] + u0.y*fpos[1] + u0.z*fpos[2] + u0.w*fpos[3]
           + u1.x*fpos[4] + u1.y*fpos[5] + u1.z*fpos[6] + u1.w*fpos[7];
        h += t0.x*gpos[0] + t0.y*gpos[1] + t0.z*gpos[2] + t0.w*gpos[3]
           + t1.x*gpos[4] + t1.y*gpos[5] + t1.z*gpos[6] + t1.w*gpos[7];
        av += a.vv[ff] * ftanh(h);
      }
    }
    av += __shfl_xor(av, 1);
    av += __shfl_xor(av, 2);
    if (sub == 0 && pos < 200) s_e[pos] = av + pbuf[b*TENC + pos];
  }
  __syncthreads();
  // softmax over 200
  float mval = (tid < 200) ? s_e[tid] : -1e30f;
  #pragma unroll
  for (int off = 32; off > 0; off >>= 1) mval = fmaxf(mval, __shfl_xor(mval, off));
  if ((tid & 63) == 0) s_red[tid >> 6] = mval;
  __syncthreads();
  const float m = fmaxf(fmaxf(s_red[0], s_red[1]), fmaxf(s_red[2], s_red[3]));
  const float ex = (tid < 200) ? __expf(s_e[tid] - m) : 0.f;
  float sv = ex;
  #pragma unroll
  for (int off = 32; off > 0; off >>= 1) sv += __shfl_xor(sv, off);
  if ((tid & 63) == 0) s_red[4 + (tid >> 6)] = sv;
  __syncthreads();
  const float inv = 1.f / (s_red[4] + s_red[5] + s_red[6] + s_red[7]);
  if (tid < 200) {
    const float awv = ex * inv;
    aw[b*TENC + tid] = awv;
    s_awn[tid] = awv;
    a.out[2048000 + b*80000 + tid*400 + s] = awv;
  }
  __syncthreads();
  // ctx = aw_new @ memory[b]   (bf16 memT [b][d][t], sequential uint4)
  #pragma unroll 1
  for (int d = tid; d < 512; d += NTHR) {
    const uint4* mp = (const uint4*)(wb + B_MEMT + b*102400 + d*200);
    float p = 0.f;
    #pragma unroll 5
    for (int q = 0; q < 25; ++q) {
      uint4 v = mp[q];
      const float* aa = s_awn + q*8;
      p += blo(v.x)*aa[0] + bhi(v.x)*aa[1] + blo(v.y)*aa[2] + bhi(v.y)*aa[3]
         + blo(v.z)*aa[4] + bhi(v.z)*aa[5] + blo(v.w)*aa[6] + bhi(v.w)*aa[7];
    }
    ctx[b*512 + d] = p;
  }
}

// ======== phase 1: J1 attn-LSTM | J2 dec-Whh partial | J3 prev outproj | J4 convs ========
// grid 1076: [0,512) J1, [512,1024) J2, [1024,1044) J3, [1044,1076) J4
__global__ __launch_bounds__(NTHR) void p1_kernel(KArgs a, int s) {
  __shared__ float sm[2560];      // [0,2048) reduce | [2048,2304) gates | J4 reuses [0,224)
  float* smred = sm;
  float* smg   = sm + 2048;
  const int tid = threadIdx.x;
  const int bid = blockIdx.x;
  float* ws = a.ws;
  const u16* wb = a.wb;
  float* ah_prev = ws + OFF_AH + ((s & 1) ? 32768 : 0);
  float* ah_new  = ws + OFF_AH + ((s & 1) ? 0 : 32768);
  float* acs = ws + OFF_ACS;
  float* dh  = ws + OFF_DH;
  float* ctx = ws + OFF_CTX;
  float* aw  = ws + OFF_AW;
  float* fbuf  = ws + OFF_FBUF;
  float* pbuf  = ws + OFF_PBUF;
  float* gpart = ws + OFF_GPART;
  float* X     = ws + OFF_X;

  if (bid < 512) {
    // J1: attn LSTM, units u0,u0+1 (rows rr = g*1024 + u0 + u)
    const int b = tid & 31, seg = tid >> 5, u0 = bid*2;
    const float* Xs = X + s*BATCH*256;
    float acc[8];
    #pragma unroll
    for (int r = 0; r < 8; ++r) acc[r] = 0.f;
    #pragma unroll 2
    for (int kc = 0; kc < 7; ++kc) {
      const float* src = (kc < 2)  ? (ctx + b*512 + kc*256)
                       : (kc == 2) ? (Xs + b*256)
                                   : (ah_prev + b*1024 + (kc-3)*256);
      float xin[32];
      loadx(src + seg*32, xin);
      #pragma unroll
      for (int r = 0; r < 8; ++r) {
        const int rr = (r>>1)*1024 + u0 + (r&1);
        const u16* wr = (kc < 3) ? (wb + B_AWIH + rr*768 + kc*256 + seg*32)
                                 : (wb + B_AWHH + rr*1024 + (kc-3)*256 + seg*32);
        acc[r] += dot32b(xin, wr);
      }
    }
    float tot = reduce8(smred, acc);
    {
      const int r2 = tid >> 5, b2 = tid & 31;
      const int rr = (r2>>1)*1024 + u0 + (r2&1);
      smg[r2*32 + b2] = tot + a.abih[rr] + a.abhh[rr];
    }
    __syncthreads();
    if (tid < 64) {
      const int u = tid >> 5, b2 = tid & 31;
      const int j = u0 + u;
      const float gi = smg[(0+u)*32+b2], gf = smg[(2+u)*32+b2];
      const float gg = smg[(4+u)*32+b2], go = smg[(6+u)*32+b2];
      const float c = sigf(gf)*acs[b2*1024+j] + sigf(gi)*ftanh(gg);
      acs[b2*1024+j] = c;
      ah_new[b2*1024+j] = sigf(go)*ftanh(c);
    }
  } else if (bid < 1024) {
    // J2: gpart = dh @ dWhh^T + biases (8 rows per block)
    const int b = tid & 31, seg = tid >> 5, j2 = bid - 512;
    float acc[8];
    #pragma unroll
    for (int r = 0; r < 8; ++r) acc[r] = 0.f;
    #pragma unroll 2
    for (int kc = 0; kc < 4; ++kc) {
      float xin[32];
      loadx(dh + b*1024 + kc*256 + seg*32, xin);
      #pragma unroll
      for (int r = 0; r < 8; ++r) {
        const int rr = j2*8 + r;
        acc[r] += dot32b(xin, wb + B_DWHH + rr*1024 + kc*256 + seg*32);
      }
    }
    float tot = reduce8(smred, acc);
    const int r2 = tid >> 5, b2 = tid & 31;
    const int rr = j2*8 + r2;
    gpart[rr*32 + b2] = tot + a.dbih[rr] + a.dbhh[rr];
  } else if (bid < 1044) {
    // J3: previous step's output projection
    if (s > 0) outproj(a, smred, dh, ctx, bid - 1024, s - 1);
  } else {
    // J4: static conv + log-prior (one batch per block)
    const int b4 = bid - 1044;
    if (tid < 224) sm[tid] = (tid >= 10 && tid < 210) ? aw[b4*TENC + tid - 10] : 0.f;
    __syncthreads();
    if (tid < 200) {
      #pragma unroll
      for (int j = 0; j < 8; ++j) {
        float p = 0.f;
        #pragma unroll
        for (int tau = 0; tau < 21; ++tau) p += sm[tid + tau] * a.F[j*21 + tau];
        fbuf[(b4*TENC + tid)*8 + j] = p;
      }
      float pp = 0.f;
      #pragma unroll
      for (int tau = 0; tau < 11; ++tau) pp += sm[tid + tau] * a.prior[tau];
      pbuf[b4*TENC + tid] = __logf(fmaxf(pp, 1e-6f));
    }
  }
}

// ======== phase 2: DCA (blocks 0..31) | dec-Wih·ah partial (blocks 32..543) ========
__global__ __launch_bounds__(NTHR) void p2_kernel(KArgs a, int s) {
  __shared__ float sm[5536];
  const int tid = threadIdx.x;
  const int bid = blockIdx.x;
  float* ws = a.ws;
  const u16* wb = a.wb;
  float* ah_new = ws + OFF_AH + ((s & 1) ? 0 : 32768);
  float* ctx = ws + OFF_CTX;
  float* aw  = ws + OFF_AW;
  float* fbuf  = ws + OFF_FBUF;
  float* pbuf  = ws + OFF_PBUF;
  float* gpart = ws + OFF_GPART;

  if (bid < 32) {
    dca_step(a, sm, bid, s, ah_new, aw, fbuf, pbuf, ctx);
  } else {
    const int b = tid & 31, seg = tid >> 5, job = bid - 32;   // 0..511
    float acc[8];
    #pragma unroll
    for (int r = 0; r < 8; ++r) acc[r] = 0.f;
    #pragma unroll 2
    for (int kc = 0; kc < 4; ++kc) {
      float xin[32];
      loadx(ah_new + b*1024 + kc*256 + seg*32, xin);
      #pragma unroll
      for (int r = 0; r < 8; ++r) {
        const int rr = job*8 + r;
        acc[r] += dot32b(xin, wb + B_DWIH + rr*1536 + kc*256 + seg*32);
      }
    }
    float tot = reduce8(sm, acc);
    const int r2 = tid >> 5, b2 = tid & 31;
    const int rr = job*8 + r2;
    gpart[rr*32 + b2] += tot;
  }
}

// ======== phase 3: finish dec LSTM (ctx columns + nonlinearity) ========
__global__ __launch_bounds__(NTHR) void p3_kernel(KArgs a, int s) {
  __shared__ float sm[2560];
  float* smred = sm;
  float* smg   = sm + 2048;
  const int tid = threadIdx.x;
  const int bid = blockIdx.x;
  float* ws = a.ws;
  const u16* wb = a.wb;
  float* dh  = ws + OFF_DH;
  float* dcs = ws + OFF_DCS;
  float* ctx = ws + OFF_CTX;
  float* gpart = ws + OFF_GPART;

  const int b = tid & 31, seg = tid >> 5, u0 = bid*2;
  float acc[8];
  #pragma unroll
  for (int r = 0; r < 8; ++r) acc[r] = 0.f;
  #pragma unroll 2
  for (int kc = 0; kc < 2; ++kc) {
    float xin[32];
    loadx(ctx + b*512 + kc*256 + seg*32, xin);
    #pragma unroll
    for (int r = 0; r < 8; ++r) {
      const int rr = (r>>1)*1024 + u0 + (r&1);
      acc[r] += dot32b(xin, wb + B_DWIH + rr*1536 + 1024 + kc*256 + seg*32);
    }
  }
  float tot = reduce8(smred, acc);
  {
    const int r2 = tid >> 5, b2 = tid & 31;
    const int rr = (r2>>1)*1024 + u0 + (r2&1);
    smg[r2*32 + b2] = tot + gpart[rr*32 + b2];
  }
  __syncthreads();
  if (tid < 64) {
    const int u = tid >> 5, b2 = tid & 31;
    const int j = u0 + u;
    const float gi = smg[(0+u)*32+b2], gf = smg[(2+u)*32+b2];
    const float gg = smg[(4+u)*32+b2], go = smg[(6+u)*32+b2];
    const float c = sigf(gf)*dcs[b2*1024+j] + sigf(gi)*ftanh(gg);
    dcs[b2*1024+j] = c;
    dh[b2*1024+j] = sigf(go)*ftanh(c);
  }
}

// ======== epilogue: final step's output projection (grid 20) ========
__global__ __launch_bounds__(NTHR) void ep_kernel(KArgs a) {
  __shared__ float sm[2048];
  float* ws = a.ws;
  outproj(a, sm, ws + OFF_DH, ws + OFF_CTX, blockIdx.x, NSTEP - 1);
}

extern "C" void kernel_launch(void* const* d_in, const int* in_sizes, int n_in,
                              void* d_out, int out_size, void* d_ws, size_t ws_size,
                              hipStream_t stream) {
  (void)in_sizes; (void)n_in; (void)out_size; (void)ws_size;
  KArgs a;
  a.mels   = (const float*)d_in[0];
  a.memory = (const float*)d_in[1];
  a.pW1 = (const float*)d_in[2];  a.pb1 = (const float*)d_in[3];
  a.pW2 = (const float*)d_in[4];  a.pb2 = (const float*)d_in[5];
  a.aWih = (const float*)d_in[6]; a.aWhh = (const float*)d_in[7];
  a.abih = (const float*)d_in[8]; a.abhh = (const float*)d_in[9];
  a.Wq = (const float*)d_in[10];  a.bq = (const float*)d_in[11];
  a.V  = (const float*)d_in[12];  a.F  = (const float*)d_in[13];
  a.U  = (const float*)d_in[14];  a.T  = (const float*)d_in[15];
  a.Tb = (const float*)d_in[16];  a.vv = (const float*)d_in[17];
  a.prior = (const float*)d_in[18];
  a.dWih = (const float*)d_in[19]; a.dWhh = (const float*)d_in[20];
  a.dbih = (const float*)d_in[21]; a.dbhh = (const float*)d_in[22];
  a.acW  = (const float*)d_in[23]; a.acb  = (const float*)d_in[24];
  a.out = (float*)d_out;
  a.ws  = (float*)((char*)d_ws + 256);
  a.wb  = (u16*)(a.ws + FLOAT_END);

  hipLaunchKernelGGL(init_kernel, dim3(512), dim3(NTHR), 0, stream, a);
  hipLaunchKernelGGL(conv_kernel, dim3(2048), dim3(NTHR), 0, stream, a);
  hipLaunchKernelGGL(prenet_kernel, dim3(NSTEP*BATCH), dim3(NTHR), 0, stream, a);
  for (int s = 0; s < NSTEP; ++s) {
    hipLaunchKernelGGL(p1_kernel, dim3(1076), dim3(NTHR), 0, stream, a, s);
    hipLaunchKernelGGL(p2_kernel, dim3(544), dim3(NTHR), 0, stream, a, s);
    hipLaunchKernelGGL(p3_kernel, dim3(512), dim3(NTHR), 0, stream, a, s);
  }
  hipLaunchKernelGGL(ep_kernel, dim3(20), dim3(NTHR), 0, stream, a);
}